// Round 13
// baseline (257.672 us; speedup 1.0000x reference)
//
#include <hip/hip_runtime.h>
#include <hip/hip_fp16.h>
#include <math.h>

typedef _Float16 half8 __attribute__((ext_vector_type(8)));
typedef float floatx4 __attribute__((ext_vector_type(4)));

__device__ __forceinline__ float leaky(float v){ return v > 0.f ? v : 0.2f*v; }

__device__ __forceinline__ float wredsum(float v){
  #pragma unroll
  for (int o=32;o>0;o>>=1) v += __shfl_xor(v,o,64);
  return v;
}

// monotone float<->uint key (order-preserving for all finite floats and +-inf)
__device__ __forceinline__ unsigned fkey(float f){
  unsigned b = __float_as_uint(f);
  return (b & 0x80000000u) ? ~b : (b | 0x80000000u);
}
__device__ __forceinline__ float funkey(unsigned u){
  unsigned b = (u & 0x80000000u) ? (u ^ 0x80000000u) : ~u;
  return __uint_as_float(b);
}
#define KEY_NEGINF 0x007FFFFFu   // fkey(-inf)

// ---------------- zeros + gmx init ----------------
__global__ void k_zero3(int* __restrict__ a, int na, int* __restrict__ b, int nb,
                        unsigned* __restrict__ gmx){
  int i = blockIdx.x*blockDim.x + threadIdx.x;
  if (i < 20) gmx[i] = KEY_NEGINF;
  if (i < na){ a[i] = 0; return; }
  i -= na;
  if (i < nb) b[i] = 0;
}

__global__ void k_hist(const int* __restrict__ dst, int* __restrict__ deg, int E){
  int i = blockIdx.x*blockDim.x + threadIdx.x;
  if (i < E) atomicAdd(&deg[dst[i]], 1);
}

__global__ __launch_bounds__(1024) void k_scan(const int* __restrict__ deg, int* __restrict__ off,
                                               int* __restrict__ cur, int N){
  __shared__ int part[1024];
  int t = threadIdx.x;
  int chunk = (N + 1023) >> 10;
  int c0 = t * chunk;
  int sum = 0;
  for (int i=0;i<chunk;i++){ int idx=c0+i; if (idx < N) sum += deg[idx]; }
  part[t] = sum;
  __syncthreads();
  for (int o=1;o<1024;o<<=1){
    int v = (t >= o) ? part[t-o] : 0;
    __syncthreads();
    part[t] += v;
    __syncthreads();
  }
  int run = part[t] - sum;   // exclusive prefix of this chunk
  for (int i=0;i<chunk;i++){
    int idx = c0+i;
    if (idx < N){ off[idx] = run; cur[idx] = run; run += deg[idx]; }
  }
  if (t == 1023) off[N] = part[1023];
}

// ---------------- scatter fused with CSR-ordered logit pre-gather ----------------
// srcs[p]=src; ge16[p*16+h] = el1[src*10+h] (h<10) else -inf.  64B aligned writes.
__global__ void k_scatterg(const int* __restrict__ src, const int* __restrict__ dst,
                           int* __restrict__ cur, const float* __restrict__ el,
                           int* __restrict__ srcs, float* __restrict__ ge16, int E){
  int i = blockIdx.x*blockDim.x + threadIdx.x;
  if (i >= E) return;
  int s0 = src[i];
  int p = atomicAdd(&cur[dst[i]], 1);
  srcs[p] = s0;
  const float* er = el + (size_t)s0*10;
  float4 v0 = make_float4(er[0], er[1], er[2], er[3]);
  float4 v1 = make_float4(er[4], er[5], er[6], er[7]);
  float4 v2 = make_float4(er[8], er[9], -INFINITY, -INFINITY);
  float4 v3 = make_float4(-INFINITY, -INFINITY, -INFINITY, -INFINITY);
  float4* o = reinterpret_cast<float4*>(ge16 + (size_t)p*16);
  o[0] = v0; o[1] = v1; o[2] = v2; o[3] = v3;
}

// ---------------- prep: fp16 casts, weight transposes, folded coef vectors ----------------
__global__ void k_prep(const float* __restrict__ x, const float* __restrict__ W1,
                       const float* __restrict__ W2,
                       const float* __restrict__ al1, const float* __restrict__ ar1,
                       const float* __restrict__ al2, const float* __restrict__ ar2,
                       __half* __restrict__ xh, __half* __restrict__ w1t, __half* __restrict__ w2t,
                       float* __restrict__ qal1, float* __restrict__ qar1,
                       float* __restrict__ qal2, float* __restrict__ qar2, int nx){
  int i = blockIdx.x*blockDim.x + threadIdx.x;
  if (i < nx){ xh[i] = __float2half(x[i]); return; }
  i -= nx;
  if (i < 640*64){ int c = i >> 6, k = i & 63; w1t[i] = __float2half(W1[k*640 + c]); return; }
  i -= 640*64;
  if (i < 128*64){ int c = i >> 6, k = i & 63; w2t[i] = __float2half(W2[k*128 + c]); return; }
  i -= 128*64;
  if (i < 1280){
    int which = i / 640; int j = i - which*640; int k = j / 10, h = j - k*10;
    const float* av = which ? ar1 : al1;
    float s = 0.f;
    for (int c=0;c<64;c++) s += W1[k*640 + h*64 + c] * av[h*64 + c];
    (which ? qar1 : qal1)[k*10 + h] = s;
    return;
  }
  i -= 1280;
  if (i < 128){
    int which = i >> 6; int k = i & 63;
    const float* av = which ? ar2 : al2;
    float s = 0.f;
    for (int c=0;c<128;c++) s += W2[k*128 + c] * av[c];
    (which ? qar2 : qal2)[k] = s;
    return;
  }
}

// ---------------- layer1 coefs + global per-head el/er maxima ----------------
__global__ __launch_bounds__(256) void k_coef1(const float* __restrict__ x,
                                               const float* __restrict__ qal, const float* __restrict__ qar,
                                               float* __restrict__ el, float* __restrict__ er,
                                               unsigned* __restrict__ gmx, int N){
  __shared__ unsigned smx[20];
  if (threadIdx.x < 20) smx[threadIdx.x] = KEY_NEGINF;
  __syncthreads();
  int n = blockIdx.x*4 + (threadIdx.x>>6);
  int lane = threadIdx.x & 63;
  float elv = -INFINITY, erv = -INFINITY;
  if (n < N){
    float xv = x[(size_t)n*64 + lane];
    #pragma unroll
    for (int h=0; h<10; h++){
      float pl = wredsum(xv * qal[lane*10 + h]);
      float pr = wredsum(xv * qar[lane*10 + h]);
      if (lane == 0){ el[n*10+h] = pl; er[n*10+h] = pr; }
      if (lane == h){ elv = pl; erv = pr; }
    }
    if (lane < 10){
      atomicMax(&smx[lane],    fkey(elv));
      atomicMax(&smx[10+lane], fkey(erv));
    }
  }
  __syncthreads();
  if (threadIdx.x < 20) atomicMax(&gmx[threadIdx.x], smx[threadIdx.x]);
}

// ---------------- layer1 aggregation: single-pass streamed logits + per-node MFMA ----------------
// w = exp(leaky(lg + er_nh) - M_h) <= 1 (M_h = leaky(max el_h + max er_h), global bound).
// Ratios w/s are exact softmax; fp16-safe (worst top weight ~exp(-4 sigma), normal range).
__global__ __launch_bounds__(64) void k_edge1(const __half* __restrict__ xh,
                                              const float* __restrict__ ge16,
                                              const float* __restrict__ er,
                                              const unsigned* __restrict__ gmx,
                                              const int* __restrict__ off,
                                              const int* __restrict__ srcs,
                                              __half* __restrict__ aggh, int N){
  const int l = threadIdx.x;
  const int n = blockIdx.x;
  const int lr = l & 15, lk = l >> 4;
  const int beg = off[n], end = off[n+1];
  const float erh = (lr < 10) ? er[n*10 + lr] : 0.f;
  const float m   = (lr < 10) ? leaky(funkey(gmx[lr]) + funkey(gmx[10+lr])) : 0.f;
  float s = 0.f;
  floatx4 acc0 = {0.f,0.f,0.f,0.f}, acc1 = {0.f,0.f,0.f,0.f};
  floatx4 acc2 = {0.f,0.f,0.f,0.f}, acc3 = {0.f,0.f,0.f,0.f};
  for (int c0 = beg; c0 < end; c0 += 32){
    int sv = (c0 + l < end) ? srcs[c0 + l] : 0;
    int sj[8];
    #pragma unroll
    for (int j=0;j<8;j++) sj[j] = __shfl(sv, lk*8 + j, 64);
    half8 aw;
    #pragma unroll
    for (int j=0;j<8;j++){
      int p = c0 + lk*8 + j;
      float wv = 0.f;
      if (p < end && lr < 10){
        float lg = ge16[(size_t)p*16 + lr];
        wv = __expf(leaky(lg + erh) - m);
      }
      aw[j] = (_Float16)wv;
      s += (float)aw[j];               // denom from the same fp16-rounded weights
    }
    half8 b0, b1, b2, b3;
    #pragma unroll
    for (int j=0;j<8;j++){
      const __half* rp = xh + (size_t)sj[j]*64;
      b0[j] = *(const _Float16*)(rp + lr);
      b1[j] = *(const _Float16*)(rp + 16 + lr);
      b2[j] = *(const _Float16*)(rp + 32 + lr);
      b3[j] = *(const _Float16*)(rp + 48 + lr);
    }
    acc0 = __builtin_amdgcn_mfma_f32_16x16x32_f16(aw, b0, acc0, 0, 0, 0);
    acc1 = __builtin_amdgcn_mfma_f32_16x16x32_f16(aw, b1, acc1, 0, 0, 0);
    acc2 = __builtin_amdgcn_mfma_f32_16x16x32_f16(aw, b2, acc2, 0, 0, 0);
    acc3 = __builtin_amdgcn_mfma_f32_16x16x32_f16(aw, b3, acc3, 0, 0, 0);
  }
  s += __shfl_xor(s,16,64);
  s += __shfl_xor(s,32,64);
  const float rs = (lr < 10 && s > 0.f) ? 1.f/s : 0.f;
  #pragma unroll
  for (int j=0;j<4;j++){
    int h = lk*4 + j;
    float rj = __shfl(rs, h, 64);
    if (h < 10){
      __half* op = aggh + (size_t)n*640 + h*64;
      op[lr]      = __float2half(acc0[j] * rj);
      op[16 + lr] = __float2half(acc1[j] * rj);
      op[32 + lr] = __float2half(acc2[j] * rj);
      op[48 + lr] = __float2half(acc3[j] * rj);
    }
  }
}

// ---------------- layer1 post-GEMM + fused layer2 coefs ----------------
__global__ __launch_bounds__(256) void k_ep1(const __half* __restrict__ aggh,
                                             const __half* __restrict__ w1t,
                                             const float* __restrict__ bias1,
                                             __half* __restrict__ h1h,
                                             const float* __restrict__ qal2,
                                             const float* __restrict__ qar2,
                                             float* __restrict__ el2, float* __restrict__ er2, int M){
  const int w = threadIdx.x >> 6, l = threadIdx.x & 63;
  const int m0 = blockIdx.x*64 + w*16;
  const int lr = l & 15, lk = l >> 4;
  int arow = m0 + lr; if (arow >= M) arow = M-1;
  float hsum[4][4];
  #pragma unroll
  for (int t=0;t<4;t++)
    #pragma unroll
    for (int j=0;j<4;j++) hsum[t][j] = 0.f;
  for (int h=0;h<10;h++){
    const __half* ap = aggh + (size_t)arow*640 + h*64;
    half8 a0 = *reinterpret_cast<const half8*>(ap + lk*8);
    half8 a1 = *reinterpret_cast<const half8*>(ap + 32 + lk*8);
    #pragma unroll
    for (int t=0;t<4;t++){
      const __half* bp = w1t + (size_t)(h*64 + t*16 + lr)*64 + lk*8;
      half8 b0 = *reinterpret_cast<const half8*>(bp);
      half8 b1 = *reinterpret_cast<const half8*>(bp + 32);
      floatx4 z = {0.f,0.f,0.f,0.f};
      z = __builtin_amdgcn_mfma_f32_16x16x32_f16(a0, b0, z, 0, 0, 0);
      z = __builtin_amdgcn_mfma_f32_16x16x32_f16(a1, b1, z, 0, 0, 0);
      float bb = bias1[h*64 + t*16 + lr];
      #pragma unroll
      for (int j=0;j<4;j++) hsum[t][j] += fmaxf(z[j] + bb, 0.f);
    }
  }
  #pragma unroll
  for (int t=0;t<4;t++)
    #pragma unroll
    for (int j=0;j<4;j++){
      int r = m0 + lk*4 + j;
      if (r < M) h1h[(size_t)r*64 + t*16 + lr] = __float2half(hsum[t][j]);
    }
  float pl[4] = {0,0,0,0}, pr[4] = {0,0,0,0};
  #pragma unroll
  for (int t=0;t<4;t++){
    float qa = qal2[t*16 + lr];
    float qr = qar2[t*16 + lr];
    #pragma unroll
    for (int j=0;j<4;j++){ pl[j] += hsum[t][j]*qa; pr[j] += hsum[t][j]*qr; }
  }
  #pragma unroll
  for (int o=1;o<16;o<<=1)
    #pragma unroll
    for (int j=0;j<4;j++){ pl[j] += __shfl_xor(pl[j],o,64); pr[j] += __shfl_xor(pr[j],o,64); }
  if (lr == 0){
    #pragma unroll
    for (int j=0;j<4;j++){
      int r = m0 + lk*4 + j;
      if (r < M){ el2[r] = pl[j]; er2[r] = pr[j]; }
    }
  }
}

// ---------------- layer2 aggregation (el2 is 80KB, L1/L2-resident; no max pass) ----------------
__global__ __launch_bounds__(64) void k_edge2(const __half* __restrict__ h1h,
                                              const float* __restrict__ el2,
                                              const float* __restrict__ er,
                                              const int* __restrict__ off,
                                              const int* __restrict__ srcs,
                                              __half* __restrict__ agg2h, int N){
  const int lane = threadIdx.x;
  const int n = blockIdx.x;
  const int beg = off[n], end = off[n+1];
  const float ern = er[n];
  float s = 0.f, acc = 0.f;
  for (int c0 = beg; c0 < end; c0 += 64){
    const bool vl = (c0 + lane < end);
    const int sv = vl ? srcs[c0 + lane] : 0;
    const float gv = vl ? el2[sv] : -INFINITY;
    const float wv = __expf(leaky(gv + ern));
    s += wv;
    const int cn = min(64, end - c0);
    for (int j = 0; j < cn; j += 8){
      const int nv = min(8, cn - j);
      float hv[8], wj[8];
      #pragma unroll
      for (int jj=0;jj<8;jj++){
        if (jj < nv){
          int sj = __shfl(sv, j+jj, 64);
          hv[jj] = __half2float(h1h[(size_t)sj*64 + lane]);
          wj[jj] = __shfl(wv, j+jj, 64);
        }
      }
      #pragma unroll
      for (int jj=0;jj<8;jj++) if (jj < nv) acc += wj[jj]*hv[jj];
    }
  }
  s = wredsum(s);
  const float rs = (s > 0.f) ? 1.f/s : 0.f;
  agg2h[(size_t)n*64 + lane] = __float2half(acc * rs);
}

// ---------------- layer2 post-GEMM: h2 = relu(agg2 @ W2 + b2) ----------------
__global__ __launch_bounds__(256) void k_l2(const __half* __restrict__ ah,
                                            const __half* __restrict__ wt,
                                            const float* __restrict__ bias2,
                                            float* __restrict__ h2, int M){
  const int w = threadIdx.x >> 6, l = threadIdx.x & 63;
  const int m0 = blockIdx.x*64 + w*16;
  const int c0 = blockIdx.y*64;
  const int lr = l & 15, lk = l >> 4;
  int arow = m0 + lr; if (arow >= M) arow = M-1;
  half8 a0 = *reinterpret_cast<const half8*>(ah + (size_t)arow*64 + lk*8);
  half8 a1 = *reinterpret_cast<const half8*>(ah + (size_t)arow*64 + 32 + lk*8);
  #pragma unroll
  for (int t=0;t<4;t++){
    const __half* bp = wt + (size_t)(c0 + t*16 + lr)*64 + lk*8;
    half8 b0 = *reinterpret_cast<const half8*>(bp);
    half8 b1 = *reinterpret_cast<const half8*>(bp + 32);
    floatx4 z = {0.f,0.f,0.f,0.f};
    z = __builtin_amdgcn_mfma_f32_16x16x32_f16(a0, b0, z, 0, 0, 0);
    z = __builtin_amdgcn_mfma_f32_16x16x32_f16(a1, b1, z, 0, 0, 0);
    float bb = bias2[c0 + t*16 + lr];
    #pragma unroll
    for (int j=0;j<4;j++){
      int r = m0 + lk*4 + j;
      if (r < M) h2[(size_t)r*128 + c0 + t*16 + lr] = fmaxf(z[j] + bb, 0.f);
    }
  }
}

// ---------------- node-parallel segmented max (pre-reduced; h2 >= 0) ----------------
__global__ __launch_bounds__(256) void k_gmax(const float* __restrict__ h2, const int* __restrict__ gid,
                                              int* __restrict__ g, int N){
  const int c = threadIdx.x & 127;
  const int q = threadIdx.x >> 7;
  int n = blockIdx.x*64 + q;
  const int nend = min(blockIdx.x*64 + 64, N);
  if (n >= nend) return;
  int curg = gid[n];
  float mx = 0.f;
  for (; n < nend; n += 2){
    int gg = gid[n];
    if (gg != curg){
      atomicMax(&g[curg*128 + c], __float_as_int(mx));
      curg = gg; mx = 0.f;
    }
    mx = fmaxf(mx, h2[(size_t)n*128 + c]);
  }
  atomicMax(&g[curg*128 + c], __float_as_int(mx));
}

// ---------------- per-graph 2-layer MLP ----------------
__global__ __launch_bounds__(128) void k_mlp(const int* __restrict__ g,
                                             const float* __restrict__ lw1, const float* __restrict__ lb1,
                                             const float* __restrict__ lw2, const float* __restrict__ lb2,
                                             float* __restrict__ out){
  int b = blockIdx.x, t = threadIdx.x;
  __shared__ float gs[128];
  __shared__ float ys[128];
  gs[t] = __int_as_float(g[b*128 + t]);
  __syncthreads();
  float y = lb1[t];
  for (int k=0;k<128;k++) y += gs[k]*lw1[k*128 + t];
  y = fmaxf(y, 0.f);
  ys[t] = y * lw2[t];
  __syncthreads();
  for (int o=64;o>0;o>>=1){
    if (t < o) ys[t] += ys[t+o];
    __syncthreads();
  }
  if (t == 0) out[b] = fmaxf(ys[0] + lb2[0], 0.f);
}

extern "C" void kernel_launch(void* const* d_in, const int* in_sizes, int n_in,
                              void* d_out, int out_size, void* d_ws, size_t ws_size,
                              hipStream_t stream){
  const float* x   = (const float*)d_in[0];
  const int*   src = (const int*)d_in[1];
  const int*   dst = (const int*)d_in[2];
  const int*   gid = (const int*)d_in[3];
  const float* W1  = (const float*)d_in[4];
  const float* al1 = (const float*)d_in[5];
  const float* ar1 = (const float*)d_in[6];
  const float* b1  = (const float*)d_in[7];
  const float* W2  = (const float*)d_in[8];
  const float* al2 = (const float*)d_in[9];
  const float* ar2 = (const float*)d_in[10];
  const float* b2  = (const float*)d_in[11];
  const float* lw1 = (const float*)d_in[12];
  const float* lb1 = (const float*)d_in[13];
  const float* lw2 = (const float*)d_in[14];
  const float* lb2 = (const float*)d_in[15];
  float* out = (float*)d_out;

  const int N = in_sizes[0] / 64;
  const int E = in_sizes[1];
  const int G = out_size;

  char* w = (char*)d_ws;
  size_t p = 0;
  auto alloc = [&](size_t bytes)->char*{ char* r = w + p; p += (bytes + 255) & ~size_t(255); return r; };
  int*      deg   = (int*)alloc((size_t)N*4);
  int*      off   = (int*)alloc((size_t)(N+1)*4);
  int*      cur   = (int*)alloc((size_t)N*4);
  int*      srcs  = (int*)alloc((size_t)E*4);
  float*    el1   = (float*)alloc((size_t)N*10*4);
  float*    er1   = (float*)alloc((size_t)N*10*4);
  unsigned* gmx   = (unsigned*)alloc(20*4);
  float*    ge16  = (float*)alloc((size_t)E*16*4);
  __half*   xh    = (__half*)alloc((size_t)N*64*2);
  __half*   w1t   = (__half*)alloc((size_t)640*64*2);
  __half*   w2t   = (__half*)alloc((size_t)128*64*2);
  float*    qal1  = (float*)alloc((size_t)640*4);
  float*    qar1  = (float*)alloc((size_t)640*4);
  float*    qal2  = (float*)alloc((size_t)64*4);
  float*    qar2  = (float*)alloc((size_t)64*4);
  __half*   aggh  = (__half*)alloc((size_t)N*640*2);
  __half*   h1h   = (__half*)alloc((size_t)N*64*2);
  __half*   agg2h = (__half*)alloc((size_t)N*64*2);
  float*    h2    = (float*)alloc((size_t)N*128*4);
  int*      gbuf  = (int*)alloc((size_t)G*128*4);
  float*    el2 = el1;
  float*    er2 = er1;

  const int nwB = (N + 3) / 4;
  const int gx  = (N + 63) / 64;
  const int prep_total = N*64 + 640*64 + 128*64 + 1280 + 128;
  const int zero_total = N + G*128;

  k_zero3  <<<dim3((zero_total+255)/256), dim3(256), 0, stream>>>(deg, N, gbuf, G*128, gmx);
  k_prep   <<<dim3((prep_total+255)/256), dim3(256), 0, stream>>>(x, W1, W2, al1, ar1, al2, ar2,
                                                                  xh, w1t, w2t, qal1, qar1, qal2, qar2, N*64);
  k_coef1  <<<dim3(nwB), dim3(256), 0, stream>>>(x, qal1, qar1, el1, er1, gmx, N);
  k_hist   <<<dim3((E+255)/256), dim3(256), 0, stream>>>(dst, deg, E);
  k_scan   <<<dim3(1),           dim3(1024),0, stream>>>(deg, off, cur, N);
  k_scatterg<<<dim3((E+255)/256), dim3(256), 0, stream>>>(src, dst, cur, el1, srcs, ge16, E);

  // layer 1
  k_edge1  <<<dim3(N), dim3(64), 0, stream>>>(xh, ge16, er1, gmx, off, srcs, aggh, N);
  k_ep1    <<<dim3(gx), dim3(256), 0, stream>>>(aggh, w1t, b1, h1h, qal2, qar2, el2, er2, N);

  // layer 2
  k_edge2  <<<dim3(N), dim3(64), 0, stream>>>(h1h, el2, er2, off, srcs, agg2h, N);
  k_l2     <<<dim3(gx, 2), dim3(256), 0, stream>>>(agg2h, w2t, b2, h2, N);

  // readout
  k_gmax   <<<dim3(gx), dim3(256), 0, stream>>>(h2, gid, gbuf, N);
  k_mlp    <<<dim3(G), dim3(128), 0, stream>>>(gbuf, lw1, lb1, lw2, lb2, out);
}

// Round 14
// 210.922 us; speedup vs baseline: 1.2216x; 1.2216x over previous
//
#include <hip/hip_runtime.h>
#include <hip/hip_fp16.h>
#include <math.h>

typedef _Float16 half8 __attribute__((ext_vector_type(8)));
typedef float floatx4 __attribute__((ext_vector_type(4)));

__device__ __forceinline__ float leaky(float v){ return v > 0.f ? v : 0.2f*v; }

__device__ __forceinline__ float wredsum(float v){
  #pragma unroll
  for (int o=32;o>0;o>>=1) v += __shfl_xor(v,o,64);
  return v;
}

// monotone float<->uint key (order-preserving)
__device__ __forceinline__ unsigned fkey(float f){
  unsigned b = __float_as_uint(f);
  return (b & 0x80000000u) ? ~b : (b | 0x80000000u);
}
__device__ __forceinline__ float funkey(unsigned u){
  unsigned b = (u & 0x80000000u) ? (u ^ 0x80000000u) : ~u;
  return __uint_as_float(b);
}
#define KEY_NEGINF 0x007FFFFFu   // fkey(-inf)

// ---------------- zeros ----------------
__global__ void k_zero2(int* __restrict__ a, int na, int* __restrict__ b, int nb){
  int i = blockIdx.x*blockDim.x + threadIdx.x;
  if (i < na){ a[i] = 0; return; }
  i -= na;
  if (i < nb) b[i] = 0;
}

// ---------------- hist + gmx reduction (block 0) ----------------
__global__ void k_hist(const int* __restrict__ dst, int* __restrict__ deg, int E,
                       const unsigned* __restrict__ pmx, unsigned* __restrict__ gmx, int nblk){
  if (blockIdx.x == 0 && threadIdx.x < 20){
    unsigned m = KEY_NEGINF;
    const unsigned* pp = pmx + threadIdx.x;
    #pragma unroll 8
    for (int b=0;b<nblk;b++) m = max(m, pp[(size_t)b*20]);
    gmx[threadIdx.x] = m;
  }
  int i = blockIdx.x*blockDim.x + threadIdx.x;
  if (i < E) atomicAdd(&deg[dst[i]], 1);
}

__global__ __launch_bounds__(1024) void k_scan(const int* __restrict__ deg, int* __restrict__ off,
                                               int* __restrict__ cur, int N){
  __shared__ int part[1024];
  int t = threadIdx.x;
  int chunk = (N + 1023) >> 10;
  int c0 = t * chunk;
  int sum = 0;
  for (int i=0;i<chunk;i++){ int idx=c0+i; if (idx < N) sum += deg[idx]; }
  part[t] = sum;
  __syncthreads();
  for (int o=1;o<1024;o<<=1){
    int v = (t >= o) ? part[t-o] : 0;
    __syncthreads();
    part[t] += v;
    __syncthreads();
  }
  int run = part[t] - sum;   // exclusive prefix of this chunk
  for (int i=0;i<chunk;i++){
    int idx = c0+i;
    if (idx < N){ off[idx] = run; cur[idx] = run; run += deg[idx]; }
  }
  if (t == 1023) off[N] = part[1023];
}

// ---------------- scatter fused with CSR-ordered logit pre-gather ----------------
__global__ void k_scatterg(const int* __restrict__ src, const int* __restrict__ dst,
                           int* __restrict__ cur, const float* __restrict__ el,
                           int* __restrict__ srcs, float* __restrict__ ge16, int E){
  int i = blockIdx.x*blockDim.x + threadIdx.x;
  if (i >= E) return;
  int s0 = src[i];
  int p = atomicAdd(&cur[dst[i]], 1);
  srcs[p] = s0;
  const float* er = el + (size_t)s0*10;
  float4 v0 = make_float4(er[0], er[1], er[2], er[3]);
  float4 v1 = make_float4(er[4], er[5], er[6], er[7]);
  float4 v2 = make_float4(er[8], er[9], -INFINITY, -INFINITY);
  float4 v3 = make_float4(-INFINITY, -INFINITY, -INFINITY, -INFINITY);
  float4* o = reinterpret_cast<float4*>(ge16 + (size_t)p*16);
  o[0] = v0; o[1] = v1; o[2] = v2; o[3] = v3;
}

// ---------------- prep: fp16 casts, weight transposes, folded coef vectors ----------------
__global__ void k_prep(const float* __restrict__ x, const float* __restrict__ W1,
                       const float* __restrict__ W2,
                       const float* __restrict__ al1, const float* __restrict__ ar1,
                       const float* __restrict__ al2, const float* __restrict__ ar2,
                       __half* __restrict__ xh, __half* __restrict__ w1t, __half* __restrict__ w2t,
                       float* __restrict__ qal1, float* __restrict__ qar1,
                       float* __restrict__ qal2, float* __restrict__ qar2, int nx){
  int i = blockIdx.x*blockDim.x + threadIdx.x;
  if (i < nx){ xh[i] = __float2half(x[i]); return; }
  i -= nx;
  if (i < 640*64){ int c = i >> 6, k = i & 63; w1t[i] = __float2half(W1[k*640 + c]); return; }
  i -= 640*64;
  if (i < 128*64){ int c = i >> 6, k = i & 63; w2t[i] = __float2half(W2[k*128 + c]); return; }
  i -= 128*64;
  if (i < 1280){
    int which = i / 640; int j = i - which*640; int k = j / 10, h = j - k*10;
    const float* av = which ? ar1 : al1;
    float s = 0.f;
    for (int c=0;c<64;c++) s += W1[k*640 + h*64 + c] * av[h*64 + c];
    (which ? qar1 : qal1)[k*10 + h] = s;
    return;
  }
  i -= 1280;
  if (i < 128){
    int which = i >> 6; int k = i & 63;
    const float* av = which ? ar2 : al2;
    float s = 0.f;
    for (int c=0;c<128;c++) s += W2[k*128 + c] * av[c];
    (which ? qar2 : qal2)[k] = s;
    return;
  }
}

// ---------------- layer1 coefs: LDS-tiled, 64 nodes/block, per-block maxes (no global atomics) ----------------
__global__ __launch_bounds__(256) void k_coef1(const float* __restrict__ x,
                                               const float* __restrict__ qal, const float* __restrict__ qar,
                                               float* __restrict__ el, float* __restrict__ er,
                                               unsigned* __restrict__ pmx, int N){
  __shared__ float xs[64][65];
  __shared__ float qs[64][20];
  __shared__ unsigned smx[20];
  const int t = threadIdx.x;
  const int base = blockIdx.x*64;
  if (t < 20) smx[t] = KEY_NEGINF;
  for (int idx = t; idx < 1280; idx += 256){
    int k = idx/20, j = idx - k*20;
    qs[k][j] = (j < 10) ? qal[k*10 + j] : qar[k*10 + (j-10)];
  }
  #pragma unroll
  for (int q=0;q<16;q++){
    int idx = t + q*256;
    int r = idx>>6, c = idx&63;
    xs[r][c] = (base + r < N) ? x[(size_t)(base+r)*64 + c] : 0.f;
  }
  __syncthreads();
  const int nl = t & 63;
  const int g  = t >> 6;       // wave-uniform output group (5 outputs of 20)
  const int n  = base + nl;
  float p[5] = {0,0,0,0,0};
  #pragma unroll 8
  for (int k=0;k<64;k++){
    float xv = xs[nl][k];
    #pragma unroll
    for (int j5=0;j5<5;j5++) p[j5] += xv * qs[k][g*5+j5];
  }
  if (n < N){
    #pragma unroll
    for (int j5=0;j5<5;j5++){
      int j = g*5 + j5;
      if (j < 10) el[(size_t)n*10 + j] = p[j5];
      else        er[(size_t)n*10 + (j-10)] = p[j5];
      atomicMax(&smx[j], fkey(p[j5]));
    }
  }
  __syncthreads();
  if (t < 20) pmx[(size_t)blockIdx.x*20 + t] = smx[t];
}

// ---------------- layer1 aggregation: single-pass streamed logits + per-node MFMA ----------------
// w = exp(leaky(lg + er_nh) - M_h) <= 1, M_h = leaky(max el_h + max er_h) (global bound).
__global__ __launch_bounds__(64) void k_edge1(const __half* __restrict__ xh,
                                              const float* __restrict__ ge16,
                                              const float* __restrict__ er,
                                              const unsigned* __restrict__ gmx,
                                              const int* __restrict__ off,
                                              const int* __restrict__ srcs,
                                              __half* __restrict__ aggh, int N){
  const int l = threadIdx.x;
  const int n = blockIdx.x;
  const int lr = l & 15, lk = l >> 4;
  const int beg = off[n], end = off[n+1];
  const float erh = (lr < 10) ? er[n*10 + lr] : 0.f;
  const float m   = (lr < 10) ? leaky(funkey(gmx[lr]) + funkey(gmx[10+lr])) : 0.f;
  float s = 0.f;
  floatx4 acc0 = {0.f,0.f,0.f,0.f}, acc1 = {0.f,0.f,0.f,0.f};
  floatx4 acc2 = {0.f,0.f,0.f,0.f}, acc3 = {0.f,0.f,0.f,0.f};
  for (int c0 = beg; c0 < end; c0 += 32){
    int sv = (c0 + l < end) ? srcs[c0 + l] : 0;
    int sj[8];
    #pragma unroll
    for (int j=0;j<8;j++) sj[j] = __shfl(sv, lk*8 + j, 64);
    half8 aw;
    #pragma unroll
    for (int j=0;j<8;j++){
      int p = c0 + lk*8 + j;
      float wv = 0.f;
      if (p < end && lr < 10){
        float lg = ge16[(size_t)p*16 + lr];
        wv = __expf(leaky(lg + erh) - m);
      }
      aw[j] = (_Float16)wv;
      s += (float)aw[j];
    }
    half8 b0, b1, b2, b3;
    #pragma unroll
    for (int j=0;j<8;j++){
      const __half* rp = xh + (size_t)sj[j]*64;
      b0[j] = *(const _Float16*)(rp + lr);
      b1[j] = *(const _Float16*)(rp + 16 + lr);
      b2[j] = *(const _Float16*)(rp + 32 + lr);
      b3[j] = *(const _Float16*)(rp + 48 + lr);
    }
    acc0 = __builtin_amdgcn_mfma_f32_16x16x32_f16(aw, b0, acc0, 0, 0, 0);
    acc1 = __builtin_amdgcn_mfma_f32_16x16x32_f16(aw, b1, acc1, 0, 0, 0);
    acc2 = __builtin_amdgcn_mfma_f32_16x16x32_f16(aw, b2, acc2, 0, 0, 0);
    acc3 = __builtin_amdgcn_mfma_f32_16x16x32_f16(aw, b3, acc3, 0, 0, 0);
  }
  s += __shfl_xor(s,16,64);
  s += __shfl_xor(s,32,64);
  const float rs = (lr < 10 && s > 0.f) ? 1.f/s : 0.f;
  #pragma unroll
  for (int j=0;j<4;j++){
    int h = lk*4 + j;
    float rj = __shfl(rs, h, 64);
    if (h < 10){
      __half* op = aggh + (size_t)n*640 + h*64;
      op[lr]      = __float2half(acc0[j] * rj);
      op[16 + lr] = __float2half(acc1[j] * rj);
      op[32 + lr] = __float2half(acc2[j] * rj);
      op[48 + lr] = __float2half(acc3[j] * rj);
    }
  }
}

// ---------------- layer1 post-GEMM + fused layer2 coefs ----------------
__global__ __launch_bounds__(256) void k_ep1(const __half* __restrict__ aggh,
                                             const __half* __restrict__ w1t,
                                             const float* __restrict__ bias1,
                                             __half* __restrict__ h1h,
                                             const float* __restrict__ qal2,
                                             const float* __restrict__ qar2,
                                             float* __restrict__ el2, float* __restrict__ er2, int M){
  const int w = threadIdx.x >> 6, l = threadIdx.x & 63;
  const int m0 = blockIdx.x*64 + w*16;
  const int lr = l & 15, lk = l >> 4;
  int arow = m0 + lr; if (arow >= M) arow = M-1;
  float hsum[4][4];
  #pragma unroll
  for (int t=0;t<4;t++)
    #pragma unroll
    for (int j=0;j<4;j++) hsum[t][j] = 0.f;
  for (int h=0;h<10;h++){
    const __half* ap = aggh + (size_t)arow*640 + h*64;
    half8 a0 = *reinterpret_cast<const half8*>(ap + lk*8);
    half8 a1 = *reinterpret_cast<const half8*>(ap + 32 + lk*8);
    #pragma unroll
    for (int t=0;t<4;t++){
      const __half* bp = w1t + (size_t)(h*64 + t*16 + lr)*64 + lk*8;
      half8 b0 = *reinterpret_cast<const half8*>(bp);
      half8 b1 = *reinterpret_cast<const half8*>(bp + 32);
      floatx4 z = {0.f,0.f,0.f,0.f};
      z = __builtin_amdgcn_mfma_f32_16x16x32_f16(a0, b0, z, 0, 0, 0);
      z = __builtin_amdgcn_mfma_f32_16x16x32_f16(a1, b1, z, 0, 0, 0);
      float bb = bias1[h*64 + t*16 + lr];
      #pragma unroll
      for (int j=0;j<4;j++) hsum[t][j] += fmaxf(z[j] + bb, 0.f);
    }
  }
  #pragma unroll
  for (int t=0;t<4;t++)
    #pragma unroll
    for (int j=0;j<4;j++){
      int r = m0 + lk*4 + j;
      if (r < M) h1h[(size_t)r*64 + t*16 + lr] = __float2half(hsum[t][j]);
    }
  float pl[4] = {0,0,0,0}, pr[4] = {0,0,0,0};
  #pragma unroll
  for (int t=0;t<4;t++){
    float qa = qal2[t*16 + lr];
    float qr = qar2[t*16 + lr];
    #pragma unroll
    for (int j=0;j<4;j++){ pl[j] += hsum[t][j]*qa; pr[j] += hsum[t][j]*qr; }
  }
  #pragma unroll
  for (int o=1;o<16;o<<=1)
    #pragma unroll
    for (int j=0;j<4;j++){ pl[j] += __shfl_xor(pl[j],o,64); pr[j] += __shfl_xor(pr[j],o,64); }
  if (lr == 0){
    #pragma unroll
    for (int j=0;j<4;j++){
      int r = m0 + lk*4 + j;
      if (r < M){ el2[r] = pl[j]; er2[r] = pr[j]; }
    }
  }
}

// ---------------- layer2 aggregation (el2 L2-resident; no max pass) ----------------
__global__ __launch_bounds__(64) void k_edge2(const __half* __restrict__ h1h,
                                              const float* __restrict__ el2,
                                              const float* __restrict__ er,
                                              const int* __restrict__ off,
                                              const int* __restrict__ srcs,
                                              __half* __restrict__ agg2h, int N){
  const int lane = threadIdx.x;
  const int n = blockIdx.x;
  const int beg = off[n], end = off[n+1];
  const float ern = er[n];
  float s = 0.f, acc = 0.f;
  for (int c0 = beg; c0 < end; c0 += 64){
    const bool vl = (c0 + lane < end);
    const int sv = vl ? srcs[c0 + lane] : 0;
    const float gv = vl ? el2[sv] : -INFINITY;
    const float wv = __expf(leaky(gv + ern));
    s += wv;
    const int cn = min(64, end - c0);
    for (int j = 0; j < cn; j += 8){
      const int nv = min(8, cn - j);
      float hv[8], wj[8];
      #pragma unroll
      for (int jj=0;jj<8;jj++){
        if (jj < nv){
          int sj = __shfl(sv, j+jj, 64);
          hv[jj] = __half2float(h1h[(size_t)sj*64 + lane]);
          wj[jj] = __shfl(wv, j+jj, 64);
        }
      }
      #pragma unroll
      for (int jj=0;jj<8;jj++) if (jj < nv) acc += wj[jj]*hv[jj];
    }
  }
  s = wredsum(s);
  const float rs = (s > 0.f) ? 1.f/s : 0.f;
  agg2h[(size_t)n*64 + lane] = __float2half(acc * rs);
}

// ---------------- layer2 post-GEMM: h2 = relu(agg2 @ W2 + b2) ----------------
__global__ __launch_bounds__(256) void k_l2(const __half* __restrict__ ah,
                                            const __half* __restrict__ wt,
                                            const float* __restrict__ bias2,
                                            float* __restrict__ h2, int M){
  const int w = threadIdx.x >> 6, l = threadIdx.x & 63;
  const int m0 = blockIdx.x*64 + w*16;
  const int c0 = blockIdx.y*64;
  const int lr = l & 15, lk = l >> 4;
  int arow = m0 + lr; if (arow >= M) arow = M-1;
  half8 a0 = *reinterpret_cast<const half8*>(ah + (size_t)arow*64 + lk*8);
  half8 a1 = *reinterpret_cast<const half8*>(ah + (size_t)arow*64 + 32 + lk*8);
  #pragma unroll
  for (int t=0;t<4;t++){
    const __half* bp = wt + (size_t)(c0 + t*16 + lr)*64 + lk*8;
    half8 b0 = *reinterpret_cast<const half8*>(bp);
    half8 b1 = *reinterpret_cast<const half8*>(bp + 32);
    floatx4 z = {0.f,0.f,0.f,0.f};
    z = __builtin_amdgcn_mfma_f32_16x16x32_f16(a0, b0, z, 0, 0, 0);
    z = __builtin_amdgcn_mfma_f32_16x16x32_f16(a1, b1, z, 0, 0, 0);
    float bb = bias2[c0 + t*16 + lr];
    #pragma unroll
    for (int j=0;j<4;j++){
      int r = m0 + lk*4 + j;
      if (r < M) h2[(size_t)r*128 + c0 + t*16 + lr] = fmaxf(z[j] + bb, 0.f);
    }
  }
}

// ---------------- node-parallel segmented max (pre-reduced; h2 >= 0) ----------------
__global__ __launch_bounds__(256) void k_gmax(const float* __restrict__ h2, const int* __restrict__ gid,
                                              int* __restrict__ g, int N){
  const int c = threadIdx.x & 127;
  const int q = threadIdx.x >> 7;
  int n = blockIdx.x*64 + q;
  const int nend = min(blockIdx.x*64 + 64, N);
  if (n >= nend) return;
  int curg = gid[n];
  float mx = 0.f;
  for (; n < nend; n += 2){
    int gg = gid[n];
    if (gg != curg){
      atomicMax(&g[curg*128 + c], __float_as_int(mx));
      curg = gg; mx = 0.f;
    }
    mx = fmaxf(mx, h2[(size_t)n*128 + c]);
  }
  atomicMax(&g[curg*128 + c], __float_as_int(mx));
}

// ---------------- per-graph 2-layer MLP ----------------
__global__ __launch_bounds__(128) void k_mlp(const int* __restrict__ g,
                                             const float* __restrict__ lw1, const float* __restrict__ lb1,
                                             const float* __restrict__ lw2, const float* __restrict__ lb2,
                                             float* __restrict__ out){
  int b = blockIdx.x, t = threadIdx.x;
  __shared__ float gs[128];
  __shared__ float ys[128];
  gs[t] = __int_as_float(g[b*128 + t]);
  __syncthreads();
  float y = lb1[t];
  for (int k=0;k<128;k++) y += gs[k]*lw1[k*128 + t];
  y = fmaxf(y, 0.f);
  ys[t] = y * lw2[t];
  __syncthreads();
  for (int o=64;o>0;o>>=1){
    if (t < o) ys[t] += ys[t+o];
    __syncthreads();
  }
  if (t == 0) out[b] = fmaxf(ys[0] + lb2[0], 0.f);
}

extern "C" void kernel_launch(void* const* d_in, const int* in_sizes, int n_in,
                              void* d_out, int out_size, void* d_ws, size_t ws_size,
                              hipStream_t stream){
  const float* x   = (const float*)d_in[0];
  const int*   src = (const int*)d_in[1];
  const int*   dst = (const int*)d_in[2];
  const int*   gid = (const int*)d_in[3];
  const float* W1  = (const float*)d_in[4];
  const float* al1 = (const float*)d_in[5];
  const float* ar1 = (const float*)d_in[6];
  const float* b1  = (const float*)d_in[7];
  const float* W2  = (const float*)d_in[8];
  const float* al2 = (const float*)d_in[9];
  const float* ar2 = (const float*)d_in[10];
  const float* b2  = (const float*)d_in[11];
  const float* lw1 = (const float*)d_in[12];
  const float* lb1 = (const float*)d_in[13];
  const float* lw2 = (const float*)d_in[14];
  const float* lb2 = (const float*)d_in[15];
  float* out = (float*)d_out;

  const int N = in_sizes[0] / 64;
  const int E = in_sizes[1];
  const int G = out_size;

  char* w = (char*)d_ws;
  size_t p = 0;
  auto alloc = [&](size_t bytes)->char*{ char* r = w + p; p += (bytes + 255) & ~size_t(255); return r; };
  int*      deg   = (int*)alloc((size_t)N*4);
  int*      off   = (int*)alloc((size_t)(N+1)*4);
  int*      cur   = (int*)alloc((size_t)N*4);
  int*      srcs  = (int*)alloc((size_t)E*4);
  float*    el1   = (float*)alloc((size_t)N*10*4);
  float*    er1   = (float*)alloc((size_t)N*10*4);
  unsigned* gmx   = (unsigned*)alloc(20*4);
  float*    ge16  = (float*)alloc((size_t)E*16*4);
  __half*   xh    = (__half*)alloc((size_t)N*64*2);
  __half*   w1t   = (__half*)alloc((size_t)640*64*2);
  __half*   w2t   = (__half*)alloc((size_t)128*64*2);
  float*    qal1  = (float*)alloc((size_t)640*4);
  float*    qar1  = (float*)alloc((size_t)640*4);
  float*    qal2  = (float*)alloc((size_t)64*4);
  float*    qar2  = (float*)alloc((size_t)64*4);
  __half*   aggh  = (__half*)alloc((size_t)N*640*2);
  __half*   h1h   = (__half*)alloc((size_t)N*64*2);
  __half*   agg2h = (__half*)alloc((size_t)N*64*2);
  float*    h2    = (float*)alloc((size_t)N*128*4);
  int*      gbuf  = (int*)alloc((size_t)G*128*4);
  const int gx  = (N + 63) / 64;
  unsigned* pmx   = (unsigned*)alloc((size_t)gx*20*4);
  float*    el2 = el1;
  float*    er2 = er1;

  const int prep_total = N*64 + 640*64 + 128*64 + 1280 + 128;
  const int zero_total = N + G*128;

  k_zero2  <<<dim3((zero_total+255)/256), dim3(256), 0, stream>>>(deg, N, gbuf, G*128);
  k_prep   <<<dim3((prep_total+255)/256), dim3(256), 0, stream>>>(x, W1, W2, al1, ar1, al2, ar2,
                                                                  xh, w1t, w2t, qal1, qar1, qal2, qar2, N*64);
  k_coef1  <<<dim3(gx), dim3(256), 0, stream>>>(x, qal1, qar1, el1, er1, pmx, N);
  k_hist   <<<dim3((E+255)/256), dim3(256), 0, stream>>>(dst, deg, E, pmx, gmx, gx);
  k_scan   <<<dim3(1),           dim3(1024),0, stream>>>(deg, off, cur, N);
  k_scatterg<<<dim3((E+255)/256), dim3(256), 0, stream>>>(src, dst, cur, el1, srcs, ge16, E);

  // layer 1
  k_edge1  <<<dim3(N), dim3(64), 0, stream>>>(xh, ge16, er1, gmx, off, srcs, aggh, N);
  k_ep1    <<<dim3(gx), dim3(256), 0, stream>>>(aggh, w1t, b1, h1h, qal2, qar2, el2, er2, N);

  // layer 2
  k_edge2  <<<dim3(N), dim3(64), 0, stream>>>(h1h, el2, er2, off, srcs, agg2h, N);
  k_l2     <<<dim3(gx, 2), dim3(256), 0, stream>>>(agg2h, w2t, b2, h2, N);

  // readout
  k_gmax   <<<dim3(gx), dim3(256), 0, stream>>>(h2, gid, gbuf, N);
  k_mlp    <<<dim3(G), dim3(128), 0, stream>>>(gbuf, lw1, lb1, lw2, lb2, out);
}